// Round 6
// baseline (420.880 us; speedup 1.0000x reference)
//
#include <hip/hip_runtime.h>

// Problem constants (from reference): N_T=5, 32x32 grid, N=1024, batch=4.
#define NT   5
#define NY   32
#define NX   32
#define NN   1024          // N = NY*NX
#define QDIM 5120          // NT * NN
#define NB   4

#define REC1 12            // W1 record: 9 stencil floats + 3 pad (48 B)
#define REC2 28            // W2 record: 25 MM floats + 3 pad (112 B)

// Native clang vector type — required by __builtin_nontemporal_store.
typedef float vfloat4 __attribute__((ext_vector_type(4)));

// Canonical stencil offset order (matches reference's offs list):
// 0:(0,0) 1:(0,1) 2:(0,-1) 3:(1,0) 4:(-1,0) 5:(1,1) 6:(1,-1) 7:(-1,1) 8:(-1,-1)
__device__ const int c_oy[9] = {0, 0, 0, 1, -1, 1, 1, -1, -1};
__device__ const int c_ox[9] = {0, 1, -1, 0, 0, 1, -1, 1, -1};

// ---------------------------------------------------------------------------
// Kernel 1: one block per (b,t). Stage the 7 input planes (kappa,mx,my,
// H00,H01,H10,H11 at fixed b,t) in LDS, compute every node's 9-point stencil
// of M = I + A (boundary dirs zeroed), then every node's 25-entry MM row
// (5x5 stencil of M*M, +I for interior t). Writes:
//   W1[(b*NT+t)*NN + n][0..8]  = stencil of M[t] at node n
//   W2[(b*NT+t)*NN + n][0..24] = row n of MM[t] (+I interior)
// Total output 3.3 MB — runtime negligible; removes ALL gather latency from
// the streaming kernel.
// ---------------------------------------------------------------------------
__global__ __launch_bounds__(256) void spde_build(const float* __restrict__ kap,
                                                  const float* __restrict__ m,
                                                  const float* __restrict__ H,
                                                  float* __restrict__ W1,
                                                  float* __restrict__ W2) {
    const int oy[9] = {0, 0, 0, 1, -1, 1, 1, -1, -1};
    const int ox[9] = {0, 1, -1, 0, 0, 1, -1, 1, -1};

    int bt = blockIdx.x;            // b*NT + t
    int t = bt % NT;
    int b = bt / NT;
    int tid = threadIdx.x;

    __shared__ float pl[7][NN];     // input planes, 28 KB
    __shared__ float st[NN * 13];   // stencils, stride 13 (coprime w/ 32 banks)

    // ---- Stage input planes (source layouts: kappa (NB,1,NN,NT),
    //      m (NB,2,NN,NT), H (NB,2,2,NN,NT); node-major, NT-strided) ----
    const float* srcs[7] = {
        kap + ((size_t)b * NN) * NT + t,
        m   + ((size_t)(b * 2 + 0) * NN) * NT + t,
        m   + ((size_t)(b * 2 + 1) * NN) * NT + t,
        H   + ((size_t)((b * 2 + 0) * 2 + 0) * NN) * NT + t,
        H   + ((size_t)((b * 2 + 0) * 2 + 1) * NN) * NT + t,
        H   + ((size_t)((b * 2 + 1) * 2 + 0) * NN) * NT + t,
        H   + ((size_t)((b * 2 + 1) * 2 + 1) * NN) * NT + t,
    };
#pragma unroll
    for (int p = 0; p < 7; ++p)
#pragma unroll
        for (int w = 0; w < 4; ++w) {
            int n = tid + 256 * w;
            pl[p][n] = srcs[p][(size_t)n * NT];
        }
    __syncthreads();

    // ---- Per-node stencil of M = I + A (DX=DY=DT=1) ----
#pragma unroll
    for (int w = 0; w < 4; ++w) {
        int n = tid + 256 * w;
        float k   = pl[0][n], mx = pl[1][n], my = pl[2][n];
        float H11 = pl[3][n], H01 = pl[4][n], H10 = pl[5][n], H22 = pl[6][n];
        float cc = 0.25f * (H01 + H10);
        float s[9];
        s[0] = 1.0f + k * k + 2.0f * H11 + 2.0f * H22;
        s[1] =  0.5f * mx - H11;
        s[2] = -0.5f * mx - H11;
        s[3] =  0.5f * my - H22;
        s[4] = -0.5f * my - H22;
        s[5] = -cc; s[6] = cc; s[7] = cc; s[8] = -cc;
        int y = n >> 5, x = n & 31;
        if (x == NX - 1) { s[1] = 0.f; s[5] = 0.f; s[7] = 0.f; }
        if (x == 0)      { s[2] = 0.f; s[6] = 0.f; s[8] = 0.f; }
        if (y == NY - 1) { s[3] = 0.f; s[5] = 0.f; s[6] = 0.f; }
        if (y == 0)      { s[4] = 0.f; s[7] = 0.f; s[8] = 0.f; }
#pragma unroll
        for (int e = 0; e < 9; ++e) st[n * 13 + e] = s[e];
        float* o1 = W1 + ((size_t)bt * NN + n) * REC1;
#pragma unroll
        for (int e = 0; e < 9; ++e) o1[e] = s[e];
    }
    __syncthreads();

    // ---- Per-node MM row (5x5), acc[(dy+2)*5 + (dx+2)] ----
#pragma unroll
    for (int w = 0; w < 4; ++w) {
        int n = tid + 256 * w;
        int ry = n >> 5, rx = n & 31;
        float acc[25];
#pragma unroll
        for (int e = 0; e < 25; ++e) acc[e] = 0.f;
#pragma unroll
        for (int d1 = 0; d1 < 9; ++d1) {
            float a = st[n * 13 + d1];          // 0 for boundary-invalid dirs
            int ky = ry + oy[d1], kx = rx + ox[d1];
            bool valid = ((unsigned)ky < NY) && ((unsigned)kx < NX);
            int k = valid ? (ky * NX + kx) : n;  // clamp; a==0 kills invalid
#pragma unroll
            for (int d2 = 0; d2 < 9; ++d2)
                acc[(oy[d1] + oy[d2] + 2) * 5 + (ox[d1] + ox[d2] + 2)]
                    += a * st[k * 13 + d2];
        }
        if (t >= 1 && t <= NT - 2) acc[12] += 1.0f;   // MM + I, interior t
        float* o2 = W2 + ((size_t)bt * NN + n) * REC2;
#pragma unroll
        for (int e = 0; e < 25; ++e) o2[e] = acc[e];
    }
}

// ---------------------------------------------------------------------------
// Kernel 2: one 256-thread block per output row (b, g = t*NN + r).
// Prologue is now 1-3 coalesced vector loads (no gathers, no math):
//   threads 0..24  load the MM row record       -> diag block image (z=1)
//   threads 32..40 load -W1[t-1] record (t>=1)  -> block t-1 image (z=0)
//   threads 48..56 load -W1[t+1] record (t<NT-1)-> block t+1 image (z=2)
// Then stream the 5120-col row: 5 x (wave-uniform select -> ds_read_b128 ->
// nontemporal global_store_dwordx4). Every byte of Q written exactly once.
// ---------------------------------------------------------------------------
__global__ __launch_bounds__(256) void spde_stream(const float* __restrict__ W1,
                                                   const float* __restrict__ W2,
                                                   float* __restrict__ Q) {
    int row = blockIdx.x;                 // 0 .. NB*NT*NN-1
    int b = row / (NT * NN);
    int g = row - b * (NT * NN);          // row within batch, 0..5119
    int t = g >> 10;
    int r = g & (NN - 1);
    int ry = r >> 5, rx = r & 31;
    int tid = threadIdx.x;

    __shared__ float img[3][NN];          // row image for col-blocks t-1,t,t+1

    // ---- zero image + issue record loads (values land after first sync) ----
    vfloat4 z4 = {0.f, 0.f, 0.f, 0.f};
    {
        vfloat4* p = (vfloat4*)&img[0][0];   // 768 slots
#pragma unroll
        for (int w = 0; w < 3; ++w) p[tid + 256 * w] = z4;
    }

    float v = 0.f;
    int dst_idx = 0;
    bool have = false;
    if (tid < 25) {
        v = W2[((size_t)(b * NT + t) * NN + r) * REC2 + tid];
        int dy = tid / 5 - 2, dx = tid % 5 - 2;
        int cy = ry + dy, cx = rx + dx;
        have = ((unsigned)cy < NY) && ((unsigned)cx < NX);
        dst_idx = 1 * NN + cy * NX + cx;
    } else if (tid >= 32 && tid < 41) {
        if (t >= 1) {
            int d = tid - 32;
            v = -W1[((size_t)(b * NT + t - 1) * NN + r) * REC1 + d];
            int cy = ry + c_oy[d], cx = rx + c_ox[d];
            have = ((unsigned)cy < NY) && ((unsigned)cx < NX);
            dst_idx = 0 * NN + cy * NX + cx;
        }
    } else if (tid >= 48 && tid < 57) {
        if (t <= NT - 2) {
            int d = tid - 48;
            v = -W1[((size_t)(b * NT + t + 1) * NN + r) * REC1 + d];
            int cy = ry + c_oy[d], cx = rx + c_ox[d];
            have = ((unsigned)cy < NY) && ((unsigned)cx < NX);
            dst_idx = 2 * NN + cy * NX + cx;
        }
    }
    __syncthreads();                      // image zeros complete
    if (have) (&img[0][0])[dst_idx] = v;  // scatter <=43 values
    __syncthreads();

    // ---- stream the full row, one 1024-col block per unrolled iteration ----
    float* dst = Q + ((size_t)b * QDIM + g) * QDIM + 4 * tid;
    const vfloat4* src = (const vfloat4*)&img[0][4 * tid];
#pragma unroll
    for (int kk = 0; kk < NT; ++kk) {
        int z = kk - t + 1;               // wave-uniform
        vfloat4 vv = ((unsigned)z < 3u) ? src[(size_t)z * (NN / 4)] : z4;
        __builtin_nontemporal_store(vv, (vfloat4*)(dst + (size_t)kk * NN));
    }
}

extern "C" void kernel_launch(void* const* d_in, const int* in_sizes, int n_in,
                              void* d_out, int out_size, void* d_ws, size_t ws_size,
                              hipStream_t stream) {
    const float* kap = (const float*)d_in[0];
    const float* m   = (const float*)d_in[1];
    const float* H   = (const float*)d_in[2];
    float* Q = (float*)d_out;

    float* W1 = (float*)d_ws;                            // 983 KB
    float* W2 = (float*)((char*)d_ws + (1 << 20));       // 2.3 MB

    spde_build<<<NB * NT, 256, 0, stream>>>(kap, m, H, W1, W2);
    spde_stream<<<NB * NT * NN, 256, 0, stream>>>(W1, W2, Q);
}

// Round 7
// 412.282 us; speedup vs baseline: 1.0209x; 1.0209x over previous
//
#include <hip/hip_runtime.h>

// Problem constants (from reference): N_T=5, 32x32 grid, N=1024, batch=4.
#define NT   5
#define NY   32
#define NX   32
#define NN   1024          // N = NY*NX
#define QDIM 5120          // NT * NN
#define NB   4

// Native clang vector type — required by __builtin_nontemporal_store
// (HIP's float4 is a class and is rejected).
typedef float vfloat4 __attribute__((ext_vector_type(4)));

// Canonical stencil offset order (matches reference's offs list):
// 0:(0,0) 1:(0,1) 2:(0,-1) 3:(1,0) 4:(-1,0) 5:(1,1) 6:(1,-1) 7:(-1,1) 8:(-1,-1)
__device__ const int c_oy[9] = {0, 0, 0, 1, -1, 1, 1, -1, -1};
__device__ const int c_ox[9] = {0, 1, -1, 0, 0, 1, -1, 1, -1};

// Stencil coefficients of M = I + A for node n, time t, batch b.
// Out-of-grid neighbor coefficients zeroed (matches VALID in reference).
__device__ __forceinline__ void stencil9(const float* __restrict__ kap,
                                         const float* __restrict__ m,
                                         const float* __restrict__ H,
                                         int b, int t, int n, float s[9]) {
    // Layouts: kappa (NB,1,NN,NT); m (NB,2,NN,NT); H (NB,2,2,NN,NT)
    float k   = kap[((size_t)b * NN + n) * NT + t];
    float mx  = m[(((size_t)b * 2 + 0) * NN + n) * NT + t];
    float my  = m[(((size_t)b * 2 + 1) * NN + n) * NT + t];
    float H11 = H[((((size_t)b * 2 + 0) * 2 + 0) * NN + n) * NT + t];
    float H01 = H[((((size_t)b * 2 + 0) * 2 + 1) * NN + n) * NT + t];
    float H10 = H[((((size_t)b * 2 + 1) * 2 + 0) * NN + n) * NT + t];
    float H22 = H[((((size_t)b * 2 + 1) * 2 + 1) * NN + n) * NT + t];
    float cc = 0.25f * (H01 + H10);                  // H12/(2 DX DY), DX=DY=1
    s[0] = 1.0f + k * k + 2.0f * H11 + 2.0f * H22;   // diag of M = 1 + c0
    s[1] =  0.5f * mx - H11;    // (0,+1)
    s[2] = -0.5f * mx - H11;    // (0,-1)
    s[3] =  0.5f * my - H22;    // (+1,0)
    s[4] = -0.5f * my - H22;    // (-1,0)
    s[5] = -cc;                 // (+1,+1)
    s[6] =  cc;                 // (+1,-1)
    s[7] =  cc;                 // (-1,+1)
    s[8] = -cc;                 // (-1,-1)
    int y = n >> 5, x = n & 31;
    if (x == NX - 1) { s[1] = 0.f; s[5] = 0.f; s[7] = 0.f; }
    if (x == 0)      { s[2] = 0.f; s[6] = 0.f; s[8] = 0.f; }
    if (y == NY - 1) { s[3] = 0.f; s[5] = 0.f; s[6] = 0.f; }
    if (y == 0)      { s[4] = 0.f; s[7] = 0.f; s[8] = 0.f; }
}

// One 256-thread block per output row (b, g = t*NN + r), single pass over Q.
// Phase 1: zero a 3-block LDS row image (blocks t-1, t, t+1) and compute the
//          11 needed stencils into LDS.
// Phase 2: scatter the <=43 nonzero values into the LDS row image.
// Phase 3: stream the 5120-column row to global: per unrolled block kk,
//          wave-uniform select (staged block vs zeros) -> float4 store.
// Every byte of Q is written exactly once; no memset pass.
//
// Measured (R5/R6 A/B): this kernel is HBM-write-bound at ~80 us for the
// 419 MB output (~5.2 TB/s; fill ceiling 6.3 TB/s => 67 us floor). Splitting
// compute into a separate pass (R6) changed nothing — prologue is free.
__global__ __launch_bounds__(256) void spde_fused(const float* __restrict__ kap,
                                                  const float* __restrict__ m,
                                                  const float* __restrict__ H,
                                                  float* __restrict__ Q) {
    const int oy[9] = {0, 0, 0, 1, -1, 1, 1, -1, -1};
    const int ox[9] = {0, 1, -1, 0, 0, 1, -1, 1, -1};

    int row = blockIdx.x;                 // 0 .. NB*NT*NN-1
    int b = row / (NT * NN);
    int g = row - b * (NT * NN);          // row within batch, 0..5119
    int t = g >> 10;
    int r = g & (NN - 1);
    int ry = r >> 5, rx = r & 31;
    int tid = threadIdx.x;

    // lds_row[z][c]: row image for column-block t-1+z (z=0..2); unused z stay 0
    __shared__ float lds_row[3][NN];
    __shared__ float sk[9][9];     // stencil of M[t] at the 9 neighbors of r
    __shared__ float moff[2][9];   // -M[t-1][r,:] and -M[t+1][r,:]

    // ---- Phase 1: zero LDS row image; threads 0..10 compute stencils ----
    {
        vfloat4 z4 = {0.f, 0.f, 0.f, 0.f};
        vfloat4* p = (vfloat4*)&lds_row[0][0];     // 768 float4 slots
#pragma unroll
        for (int w = 0; w < 3; ++w) p[tid + 256 * w] = z4;
    }
    if (tid < 9) {
        int ky = ry + c_oy[tid], kx = rx + c_ox[tid];
        bool valid = ((unsigned)ky < NY) && ((unsigned)kx < NX);
        int k = valid ? (ky * NX + kx) : r;   // clamp; invalid path killed by sr==0
        float s[9];
        stencil9(kap, m, H, b, t, k, s);
#pragma unroll
        for (int e = 0; e < 9; ++e)
            sk[tid][(oy[e] + 1) * 3 + (ox[e] + 1)] = s[e];
    } else if (tid == 9) {
        float s[9] = {0,0,0,0,0,0,0,0,0};
        if (t >= 1) stencil9(kap, m, H, b, t - 1, r, s);
#pragma unroll
        for (int e = 0; e < 9; ++e) moff[0][e] = -s[e];
    } else if (tid == 10) {
        float s[9] = {0,0,0,0,0,0,0,0,0};
        if (t <= NT - 2) stencil9(kap, m, H, b, t + 1, r, s);
#pragma unroll
        for (int e = 0; e < 9; ++e) moff[1][e] = -s[e];
    }
    __syncthreads();

    // ---- Phase 2: scatter nonzeros into the LDS row image ----
    if (tid < 25) {
        // Diag block (z=1): entry (dy,dx) of row r of MM[t] (+I interior)
        int dy = tid / 5 - 2, dx = tid % 5 - 2;
        float a = 0.f;
#pragma unroll
        for (int d1 = 0; d1 < 9; ++d1) {
            int dy2 = dy - oy[d1], dx2 = dx - ox[d1];
            if (dy2 >= -1 && dy2 <= 1 && dx2 >= -1 && dx2 <= 1) {
                a += sk[0][(oy[d1] + 1) * 3 + (ox[d1] + 1)]
                   * sk[d1][(dy2 + 1) * 3 + (dx2 + 1)];
            }
        }
        if (tid == 12 && t >= 1 && t <= NT - 2) a += 1.0f;  // MM + I, interior t
        int cy = ry + dy, cx = rx + dx;
        if ((unsigned)cy < NY && (unsigned)cx < NX)
            lds_row[1][cy * NX + cx] = a;
    } else if (tid >= 32 && tid < 41) {
        // Block t-1 (z=0): -M[t-1][r, c]
        if (t >= 1) {
            int d = tid - 32;
            int cy = ry + c_oy[d], cx = rx + c_ox[d];
            if ((unsigned)cy < NY && (unsigned)cx < NX)
                lds_row[0][cy * NX + cx] = moff[0][d];
        }
    } else if (tid >= 48 && tid < 57) {
        // Block t+1 (z=2): -M[t+1][r, c]
        if (t <= NT - 2) {
            int d = tid - 48;
            int cy = ry + c_oy[d], cx = rx + c_ox[d];
            if ((unsigned)cy < NY && (unsigned)cx < NX)
                lds_row[2][cy * NX + cx] = moff[1][d];
        }
    }
    __syncthreads();

    // ---- Phase 3: stream the full row, one 1024-col block per iteration ----
    // Thread tid covers columns [4*tid, 4*tid+3] of each block; block kk's
    // staged image index z = kk - t + 1 is wave-uniform.
    float* dst = Q + ((size_t)b * QDIM + g) * QDIM + 4 * tid;
    const vfloat4* src = (const vfloat4*)&lds_row[0][4 * tid];
    vfloat4 z4 = {0.f, 0.f, 0.f, 0.f};
#pragma unroll
    for (int kk = 0; kk < NT; ++kk) {
        int z = kk - t + 1;
        vfloat4 v = ((unsigned)z < 3u) ? src[(size_t)z * (NN / 4)] : z4;
        __builtin_nontemporal_store(v, (vfloat4*)(dst + (size_t)kk * NN));
    }
}

extern "C" void kernel_launch(void* const* d_in, const int* in_sizes, int n_in,
                              void* d_out, int out_size, void* d_ws, size_t ws_size,
                              hipStream_t stream) {
    const float* kap = (const float*)d_in[0];
    const float* m   = (const float*)d_in[1];
    const float* H   = (const float*)d_in[2];
    float* Q = (float*)d_out;

    int nrows = NB * NT * NN;  // 20480 blocks, one per output row
    spde_fused<<<nrows, 256, 0, stream>>>(kap, m, H, Q);
}